// Round 5
// baseline (187.720 us; speedup 1.0000x reference)
//
#include <hip/hip_runtime.h>
#include <hip/hip_bf16.h>

typedef __bf16 bf16_t;
typedef __attribute__((ext_vector_type(8))) __bf16 bf16x8;
typedef __attribute__((ext_vector_type(4))) __bf16 bf16x4;
typedef __attribute__((ext_vector_type(4))) short s16x4;
typedef __attribute__((ext_vector_type(4))) float f32x4;
typedef __attribute__((ext_vector_type(4))) _Float16 f16x4;

#define NTOK 4096
#define DIM  768
#define NH   12
#define HD   64
#define NSPLIT 4
#define KHALF (NTOK / NSPLIT)   // 1024 -> NIT=16
#define XSZ  (NTOK * DIM)       // 3,145,728
#define WQSZ (3 * DIM * DIM)    // 1,769,472
#define WPSZ (DIM * DIM)        //   589,824
// 0.125 * log2(e): folded into Q so S^T is directly in log2 domain
#define SCALE_L2E 0.18033688011112042f
// static softmax shift (shift-invariant, no overflow for |st|<~15)
#define SOFTMAX_C 12.0f

__device__ __forceinline__ bf16x8 load8(const bf16_t* p) {
    return *reinterpret_cast<const bf16x8*>(p);
}
__device__ __forceinline__ void store8(bf16_t* p, bf16x8 v) {
    *reinterpret_cast<bf16x8*>(p) = v;
}
// async global->LDS, 16B per lane; LDS dest = wave-uniform base + lane*16
__device__ __forceinline__ void gl2lds16(const bf16_t* g, bf16_t* l) {
    __builtin_amdgcn_global_load_lds(
        (const __attribute__((address_space(1))) void*)g,
        (__attribute__((address_space(3))) void*)l, 16, 0, 0);
}

// ---------------------------------------------------------------------------
// Convert fp32 inputs to bf16 once (memory-bound, ~33 MB total).
// ---------------------------------------------------------------------------
__global__ __launch_bounds__(256) void cvt_kernel(
    const float* __restrict__ x, const float* __restrict__ wq,
    const float* __restrict__ wp,
    bf16_t* __restrict__ xb, bf16_t* __restrict__ wqb, bf16_t* __restrict__ wpb)
{
    size_t i = ((size_t)blockIdx.x * 256 + threadIdx.x) * 4;
    const float* src; bf16_t* dst; size_t off;
    if (i < XSZ)             { src = x;  dst = xb;  off = i; }
    else if (i < XSZ + WQSZ) { src = wq; dst = wqb; off = i - XSZ; }
    else                     { src = wp; dst = wpb; off = i - XSZ - WQSZ; }
    float4 v = *reinterpret_cast<const float4*>(src + off);
    bf16x4 o = { (bf16_t)v.x, (bf16_t)v.y, (bf16_t)v.z, (bf16_t)v.w };
    *reinterpret_cast<bf16x4*>(dst + off) = o;
}

// ---------------------------------------------------------------------------
// QKV GEMM, m97-style: 128x128 tile, BK=32, staging via global_load_lds
// width=16 into CONTIGUOUS [128][32] LDS. 2 barriers per K-step.
// Epilogue scatter: t=0: Q[h][m][d] (*SCALE_L2E)  t=1: K[h][m][d]
//                   t=2: Vt[h][d][m] (8B stores)
// ---------------------------------------------------------------------------
__global__ __launch_bounds__(256) void qkv_gemm_kernel(
    const bf16_t* __restrict__ X, const bf16_t* __restrict__ W,
    bf16_t* __restrict__ Qo, bf16_t* __restrict__ Ko, bf16_t* __restrict__ Vt)
{
    __shared__ __align__(16) bf16_t As[128 * 32];
    __shared__ __align__(16) bf16_t Bs[128 * 32];
    const int tid  = threadIdx.x;
    const int wave = tid >> 6, lane = tid & 63;
    const int lr = lane & 15, lq = lane >> 4;
    const int M0 = blockIdx.x * 128;
    const int N0 = blockIdx.y * 128;
    const int wm = (wave >> 1) * 64, wn = (wave & 1) * 64;

    const int g_row = wave * 32 + (lane >> 2);     // + c*16
    const int g_col = (lane & 3) * 8;

    f32x4 acc[4][4] = {};

    for (int k0 = 0; k0 < DIM; k0 += 32) {
        #pragma unroll
        for (int c = 0; c < 2; ++c) {
            gl2lds16(&X[(size_t)(M0 + g_row + c * 16) * DIM + k0 + g_col],
                     &As[(wave * 32 + c * 16) * 32]);
            gl2lds16(&W[(size_t)(N0 + g_row + c * 16) * DIM + k0 + g_col],
                     &Bs[(wave * 32 + c * 16) * 32]);
        }
        __syncthreads();   // drains vmcnt: LDS tiles complete
        bf16x8 af[4], bfr[4];
        #pragma unroll
        for (int i = 0; i < 4; ++i) af[i]  = load8(&As[(wm + i * 16 + lr) * 32 + lq * 8]);
        #pragma unroll
        for (int i = 0; i < 4; ++i) bfr[i] = load8(&Bs[(wn + i * 16 + lr) * 32 + lq * 8]);
        #pragma unroll
        for (int r = 0; r < 4; ++r)
            #pragma unroll
            for (int c = 0; c < 4; ++c)
                acc[r][c] = __builtin_amdgcn_mfma_f32_16x16x32_bf16(af[r], bfr[c], acc[r][c], 0, 0, 0);
        __syncthreads();   // protect LDS before next overwrite
    }

    const int t = N0 / DIM;      // uniform per block (768 % 128 == 0)
    if (t == 2) {
        #pragma unroll
        for (int r = 0; r < 4; ++r)
            #pragma unroll
            for (int c = 0; c < 4; ++c) {
                int m0 = M0 + wm + r * 16 + lq * 4;
                int rem = N0 + wn + c * 16 + lr - 2 * DIM;
                int hh = rem >> 6, d = rem & 63;
                bf16x4 v = { (bf16_t)acc[r][c][0], (bf16_t)acc[r][c][1],
                             (bf16_t)acc[r][c][2], (bf16_t)acc[r][c][3] };
                *reinterpret_cast<bf16x4*>(&Vt[((size_t)hh * HD + d) * NTOK + m0]) = v;
            }
    } else {
        #pragma unroll
        for (int r = 0; r < 4; ++r)
            #pragma unroll
            for (int c = 0; c < 4; ++c)
                #pragma unroll
                for (int reg = 0; reg < 4; ++reg) {
                    int m = M0 + wm + r * 16 + lq * 4 + reg;
                    int rem = N0 + wn + c * 16 + lr - t * DIM;
                    int hh = rem >> 6, d = rem & 63;
                    float v = acc[r][c][reg];
                    if (t == 0) Qo[(hh * NTOK + m) * HD + d] = (bf16_t)(v * SCALE_L2E);
                    else        Ko[(hh * NTOK + m) * HD + d] = (bf16_t)v;
                }
    }
}

// ---------------------------------------------------------------------------
// Flash attention, S^T form, static-shift softmax, split-K=4.
// XOR-swizzled stride-64 LDS: cell (row, swgroup) holds original column group
// swgroup ^ (row&7).  READS (unchanged from measured-good r3/r4):
//   K frag: kc0/kc1,  V frag: vc[g]  -- per-lane constants.
// STAGING now via global_load_lds DIRECT to LDS (zero staging VGPRs):
//   LDS dest stays LINEAR (wave-uniform base + lane*16, required by HW);
//   the SWIZZLE moves to the per-lane GLOBAL source address. Wave w, call c,
//   lane l stages LDS bytes [base(w,c) + l*16): row = w*16+c*8+l/8 (row&7 =
//   l/8), swgroup = l%8  => original col group = (l%8)^(l/8), a lane const.
// Race analysis (one barrier/iter): stage(it+1 -> buf^1) issues after
// barrier(end it-1), by which point all waves finished reading buf^1 in
// compute(it-1). __syncthreads drains each wave's own vmcnt, so after
// barrier(end it) the whole of buf^1 is complete before compute(it+1).
// Compute fused per key-group g: QK MFMA -> exp2 -> pack -> PV MFMA, so only
// za/zb (8 f32) are live instead of sa/sb[4][4] (32): register pressure was
// the occupancy cap (r4: 2 blocks/CU from ~176 unified regs; grid no lever).
// QK accumulators init to -SOFTMAX_C (sub folded into MFMA C-in).
// NOTE: plain __launch_bounds__(256); (256,N) hints force arch/acc split and
// spill (r2: 48 VGPR, 432 MB scratch, 242 us).
// ---------------------------------------------------------------------------
__global__ __launch_bounds__(256) void flash_attn_kernel(
    const bf16_t* __restrict__ Qb, const bf16_t* __restrict__ Kb,
    const bf16_t* __restrict__ Vtb, _Float16* __restrict__ Opart,
    float* __restrict__ Lpart)
{
    __shared__ __align__(16) bf16_t Ks[2][64 * 64];   // [key][d]  swizzled
    __shared__ __align__(16) bf16_t Vs[2][64 * 64];   // [d][key]  swizzled
    const int tid  = threadIdx.x;
    const int wave = tid >> 6, lane = tid & 63;
    const int lr = lane & 15, lq = lane >> 4;
    const int h  = blockIdx.y;
    const int q0 = blockIdx.x * 128;
    const int sp = blockIdx.z;
    const int kt0 = sp * KHALF;
    const int NIT = KHALF / 64;     // 16

    // read-side swizzle constants (elements) -- unchanged from r3/r4
    const int kc0 = (lq ^ (lr & 7)) * 8;                             // K frag d 0..31
    const int kc1 = ((4 + lq) ^ (lr & 7)) * 8;                       // K frag d 32..63
    int vc[4];
    #pragma unroll
    for (int g = 0; g < 4; ++g)
        vc[g] = ((2 * g + (lq >> 1)) ^ (lr & 7)) * 8 + (lq & 1) * 4; // V frag keys

    // staging: wave w covers rows w*16..w*16+16 of the 64-row tile in 2 calls
    const int srow = lane >> 3;                        // 0..7
    const int scol = ((lane & 7) ^ srow) * 8;          // inverse-swizzled col
    const bf16_t* kbase = &Kb[(size_t)h * NTOK * HD];
    const bf16_t* vbase = &Vtb[(size_t)h * HD * NTOK];
    // per-lane global element offsets (tile-invariant part)
    const size_t kofA = (size_t)(wave * 16 + srow) * HD + scol;
    const size_t kofB = kofA + (size_t)8 * HD;
    const size_t vofA = (size_t)(wave * 16 + srow) * NTOK + scol;
    const size_t vofB = vofA + (size_t)8 * NTOK;
    // wave-uniform LDS dests
    const int ldA = (wave * 16) * 64;        // + buf select
    const int ldB = (wave * 16 + 8) * 64;

    // Q as B-operand of S^T for two q-subtiles (rows +lr and +16+lr)
    const bf16_t* qrowA = &Qb[((size_t)h * NTOK + q0 + wave * 32 + lr) * HD];
    const bf16_t* qrowB = qrowA + 16 * HD;
    bf16x8 qa0 = load8(&qrowA[lq * 8]);
    bf16x8 qa1 = load8(&qrowA[32 + lq * 8]);
    bf16x8 qb0 = load8(&qrowB[lq * 8]);
    bf16x8 qb1 = load8(&qrowB[32 + lq * 8]);

    float la = 0.f, lb = 0.f;
    f32x4 oA[4] = {}, oB[4] = {};
    const f32x4 mc = { -SOFTMAX_C, -SOFTMAX_C, -SOFTMAX_C, -SOFTMAX_C };

    // prologue: stage tile 0 into buf 0
    {
        const bf16_t* kp = kbase + (size_t)kt0 * HD;
        const bf16_t* vp = vbase + kt0;
        gl2lds16(kp + kofA, &Ks[0][ldA]);
        gl2lds16(kp + kofB, &Ks[0][ldB]);
        gl2lds16(vp + vofA, &Vs[0][ldA]);
        gl2lds16(vp + vofB, &Vs[0][ldB]);
    }
    __syncthreads();

    for (int it = 0; it < NIT; ++it) {
        const int buf = it & 1;

        // stage next tile direct to LDS buf^1; completes by next barrier
        if (it + 1 < NIT) {
            const int kn = kt0 + (it + 1) * 64;
            const bf16_t* kp = kbase + (size_t)kn * HD;
            const bf16_t* vp = vbase + kn;
            gl2lds16(kp + kofA, &Ks[buf ^ 1][ldA]);
            gl2lds16(kp + kofB, &Ks[buf ^ 1][ldB]);
            gl2lds16(vp + vofA, &Vs[buf ^ 1][ldA]);
            gl2lds16(vp + vofB, &Vs[buf ^ 1][ldB]);
        }

        // fused per key-group: QK -> exp2 -> pack -> PV (za/zb only live regs)
        #pragma unroll
        for (int g = 0; g < 4; ++g) {
            bf16x8 k0 = load8(&Ks[buf][(g * 16 + lr) * 64 + kc0]);
            bf16x8 k1 = load8(&Ks[buf][(g * 16 + lr) * 64 + kc1]);
            f32x4 za = mc, zb = mc;
            __builtin_amdgcn_s_setprio(1);
            za = __builtin_amdgcn_mfma_f32_16x16x32_bf16(k0, qa0, za, 0, 0, 0);
            za = __builtin_amdgcn_mfma_f32_16x16x32_bf16(k1, qa1, za, 0, 0, 0);
            zb = __builtin_amdgcn_mfma_f32_16x16x32_bf16(k0, qb0, zb, 0, 0, 0);
            zb = __builtin_amdgcn_mfma_f32_16x16x32_bf16(k1, qb1, zb, 0, 0, 0);
            __builtin_amdgcn_s_setprio(0);
            #pragma unroll
            for (int r = 0; r < 4; ++r) {
                za[r] = __builtin_amdgcn_exp2f(za[r]);
                la += za[r];
                zb[r] = __builtin_amdgcn_exp2f(zb[r]);
                lb += zb[r];
            }
            bf16x4 pa = { (bf16_t)za[0], (bf16_t)za[1],
                          (bf16_t)za[2], (bf16_t)za[3] };
            bf16x4 pb = { (bf16_t)zb[0], (bf16_t)zb[1],
                          (bf16_t)zb[2], (bf16_t)zb[3] };
            s16x4 psa = __builtin_bit_cast(s16x4, pa);
            s16x4 psb = __builtin_bit_cast(s16x4, pb);
            __builtin_amdgcn_s_setprio(1);
            #pragma unroll
            for (int dt = 0; dt < 4; ++dt) {
                s16x4 va = *reinterpret_cast<const s16x4*>(
                    &Vs[buf][(dt * 16 + lr) * 64 + vc[g]]);
                oA[dt] = __builtin_amdgcn_mfma_f32_16x16x16bf16_1k(va, psa, oA[dt], 0, 0, 0);
                oB[dt] = __builtin_amdgcn_mfma_f32_16x16x16bf16_1k(va, psb, oB[dt], 0, 0, 0);
            }
            __builtin_amdgcn_s_setprio(0);
        }

        __syncthreads();   // drains own gl2lds (next buf ready) + protects buf
    }

    la += __shfl_xor(la, 16); la += __shfl_xor(la, 32);
    lb += __shfl_xor(lb, 16); lb += __shfl_xor(lb, 32);
    const int ma = q0 + wave * 32 + lr;
    const int mb = ma + 16;
    if (lq == 0) {
        Lpart[((size_t)sp * NH + h) * NTOK + ma] = la;
        Lpart[((size_t)sp * NH + h) * NTOK + mb] = lb;
    }
    _Float16* oa = &Opart[((size_t)sp * NTOK + ma) * DIM + h * HD];
    _Float16* ob = &Opart[((size_t)sp * NTOK + mb) * DIM + h * HD];
    #pragma unroll
    for (int dt = 0; dt < 4; ++dt) {
        f16x4 va = { (_Float16)oA[dt][0], (_Float16)oA[dt][1],
                     (_Float16)oA[dt][2], (_Float16)oA[dt][3] };
        f16x4 vb = { (_Float16)oB[dt][0], (_Float16)oB[dt][1],
                     (_Float16)oB[dt][2], (_Float16)oB[dt][3] };
        *reinterpret_cast<f16x4*>(&oa[dt * 16 + lq * 4]) = va;
        *reinterpret_cast<f16x4*>(&ob[dt * 16 + lq * 4]) = vb;
    }
}

// ---------------------------------------------------------------------------
// Split-K combine: one pass over the NSPLIT fp16 partials, normalize by the
// summed softmax denominators, emit bf16 A for the proj GEMM.
// ---------------------------------------------------------------------------
__global__ __launch_bounds__(256) void combine_kernel(
    const _Float16* __restrict__ Opart, const float* __restrict__ Lpart,
    bf16_t* __restrict__ Ab)
{
    int idx = blockIdx.x * 256 + threadIdx.x;       // over NTOK*DIM/4
    int m = idx / (DIM / 4);
    int c = (idx - m * (DIM / 4)) * 4;
    int hh = c >> 6;
    float l = 0.f;
    #pragma unroll
    for (int s = 0; s < NSPLIT; ++s)
        l += Lpart[((size_t)s * NH + hh) * NTOK + m];
    float rv = 1.f / l;
    float a0 = 0.f, a1 = 0.f, a2 = 0.f, a3 = 0.f;
    #pragma unroll
    for (int s = 0; s < NSPLIT; ++s) {
        f16x4 v = *reinterpret_cast<const f16x4*>(
            &Opart[((size_t)s * NTOK + m) * DIM + c]);
        a0 += (float)v[0]; a1 += (float)v[1];
        a2 += (float)v[2]; a3 += (float)v[3];
    }
    bf16x4 o = { (bf16_t)(a0 * rv), (bf16_t)(a1 * rv),
                 (bf16_t)(a2 * rv), (bf16_t)(a3 * rv) };
    *reinterpret_cast<bf16x4*>(&Ab[(size_t)m * DIM + c]) = o;
}

// ---------------------------------------------------------------------------
// Proj GEMM: plain bf16 GEMM out = A @ Wp^T + bias, 64x64 tile, BK=32,
// gl2lds16 staging into contiguous [64][32] LDS (bank-uniform for b128
// frag reads).
// ---------------------------------------------------------------------------
__global__ __launch_bounds__(256) void proj_gemm_kernel(
    const bf16_t* __restrict__ A, const bf16_t* __restrict__ W,
    const float* __restrict__ bias, float* __restrict__ out)
{
    __shared__ __align__(16) bf16_t As[64 * 32];
    __shared__ __align__(16) bf16_t Bs[64 * 32];
    const int tid  = threadIdx.x;
    const int wave = tid >> 6, lane = tid & 63;
    const int lr = lane & 15, lq = lane >> 4;
    const int M0 = blockIdx.x * 64;
    const int N0 = blockIdx.y * 64;
    const int wr = (wave >> 1) * 32, wc = (wave & 1) * 32;
    const int g_row = tid >> 2;           // 0..63
    const int g_col = (tid & 3) * 8;

    f32x4 acc[2][2] = {};

    for (int k0 = 0; k0 < DIM; k0 += 32) {
        gl2lds16(&A[(size_t)(M0 + g_row) * DIM + k0 + g_col], &As[wave * 512]);
        gl2lds16(&W[(size_t)(N0 + g_row) * DIM + k0 + g_col], &Bs[wave * 512]);
        __syncthreads();
        bf16x8 a0 = load8(&As[(wr + lr) * 32 + lq * 8]);
        bf16x8 a1 = load8(&As[(wr + 16 + lr) * 32 + lq * 8]);
        bf16x8 b0 = load8(&Bs[(wc + lr) * 32 + lq * 8]);
        bf16x8 b1 = load8(&Bs[(wc + 16 + lr) * 32 + lq * 8]);
        acc[0][0] = __builtin_amdgcn_mfma_f32_16x16x32_bf16(a0, b0, acc[0][0], 0, 0, 0);
        acc[0][1] = __builtin_amdgcn_mfma_f32_16x16x32_bf16(a0, b1, acc[0][1], 0, 0, 0);
        acc[1][0] = __builtin_amdgcn_mfma_f32_16x16x32_bf16(a1, b0, acc[1][0], 0, 0, 0);
        acc[1][1] = __builtin_amdgcn_mfma_f32_16x16x32_bf16(a1, b1, acc[1][1], 0, 0, 0);
        __syncthreads();
    }

    #pragma unroll
    for (int r = 0; r < 2; ++r)
        #pragma unroll
        for (int c = 0; c < 2; ++c)
            #pragma unroll
            for (int reg = 0; reg < 4; ++reg) {
                int m = M0 + wr + r * 16 + lq * 4 + reg;
                int n = N0 + wc + c * 16 + lr;
                out[(size_t)m * DIM + n] = acc[r][c][reg] + bias[n];
            }
}

// ---------------------------------------------------------------------------
// Workspace layout (55,050,240 B total -- strictly within the proven
// 55,443,456 B envelope from rounds 2/3):
//   [0, 3sz)          Q | K | Vt   (flash inputs; Q reused as Ab after flash)
//   [3sz, +XSZ*2)     xb           (dead after qkv; Lpart lives at its base)
//   [.., +WQSZ*2)     wqb          (dead after qkv)
//   [.., +WPSZ*2)     wpb          (live until proj)
//   [.., +25.2MB)     Opart fp16   (NSPLIT=4)
// ---------------------------------------------------------------------------
extern "C" void kernel_launch(void* const* d_in, const int* in_sizes, int n_in,
                              void* d_out, int out_size, void* d_ws, size_t ws_size,
                              hipStream_t stream)
{
    const float* x      = (const float*)d_in[0];
    const float* w_qkv  = (const float*)d_in[1];
    const float* w_proj = (const float*)d_in[2];
    const float* b_proj = (const float*)d_in[3];
    float* out = (float*)d_out;

    char* ws = (char*)d_ws;
    const size_t sz = (size_t)NH * NTOK * HD * sizeof(bf16_t);  // 6,291,456 B
    bf16_t*   Q     = (bf16_t*)(ws);
    bf16_t*   K     = (bf16_t*)(ws + sz);
    bf16_t*   Vt    = (bf16_t*)(ws + 2 * sz);
    bf16_t*   xb    = (bf16_t*)(ws + 3 * sz);
    bf16_t*   wqb   = (bf16_t*)(ws + 3 * sz + (size_t)XSZ * 2);
    bf16_t*   wpb   = (bf16_t*)(ws + 3 * sz + (size_t)(XSZ + WQSZ) * 2);
    _Float16* Opart = (_Float16*)(ws + 3 * sz + (size_t)(XSZ + WQSZ + WPSZ) * 2);
    float*    Lpart = (float*)xb;   // xb dead after qkv_gemm; 786,432 B fits
    bf16_t*   Ab    = Q;            // Q dead after flash_attn

    cvt_kernel<<<dim3((XSZ + WQSZ + WPSZ) / 1024), 256, 0, stream>>>(
        x, w_qkv, w_proj, xb, wqb, wpb);
    qkv_gemm_kernel<<<dim3(NTOK / 128, (3 * DIM) / 128), 256, 0, stream>>>(
        xb, wqb, Q, K, Vt);
    flash_attn_kernel<<<dim3(NTOK / 128, NH, NSPLIT), 256, 0, stream>>>(
        Q, K, Vt, Opart, Lpart);
    combine_kernel<<<dim3((NTOK * DIM / 4) / 256), 256, 0, stream>>>(
        Opart, Lpart, Ab);
    proj_gemm_kernel<<<dim3(NTOK / 64, DIM / 64), 256, 0, stream>>>(
        Ab, wpb, b_proj, out);
}

// Round 6
// 187.503 us; speedup vs baseline: 1.0012x; 1.0012x over previous
//
#include <hip/hip_runtime.h>
#include <hip/hip_bf16.h>

typedef __bf16 bf16_t;
typedef __attribute__((ext_vector_type(8))) __bf16 bf16x8;
typedef __attribute__((ext_vector_type(4))) __bf16 bf16x4;
typedef __attribute__((ext_vector_type(4))) short s16x4;
typedef __attribute__((ext_vector_type(4))) float f32x4;
typedef __attribute__((ext_vector_type(4))) _Float16 f16x4;

#define NTOK 4096
#define DIM  768
#define NH   12
#define HD   64
#define NSPLIT 4
#define KHALF (NTOK / NSPLIT)   // 1024 -> NIT=16
#define XSZ  (NTOK * DIM)       // 3,145,728
#define WQSZ (3 * DIM * DIM)    // 1,769,472
#define WPSZ (DIM * DIM)        //   589,824
// 0.125 * log2(e): folded into Q so S^T is directly in log2 domain
#define SCALE_L2E 0.18033688011112042f
// static softmax shift (shift-invariant, no overflow for |st|<~15)
#define SOFTMAX_C 12.0f

__device__ __forceinline__ bf16x8 load8(const bf16_t* p) {
    return *reinterpret_cast<const bf16x8*>(p);
}
__device__ __forceinline__ void store8(bf16_t* p, bf16x8 v) {
    *reinterpret_cast<bf16x8*>(p) = v;
}
// async global->LDS, 16B per lane; LDS dest = wave-uniform base + lane*16
__device__ __forceinline__ void gl2lds16(const bf16_t* g, bf16_t* l) {
    __builtin_amdgcn_global_load_lds(
        (const __attribute__((address_space(1))) void*)g,
        (__attribute__((address_space(3))) void*)l, 16, 0, 0);
}

// ---------------------------------------------------------------------------
// Convert fp32 inputs to bf16 once (memory-bound, ~33 MB total).
// ---------------------------------------------------------------------------
__global__ __launch_bounds__(256) void cvt_kernel(
    const float* __restrict__ x, const float* __restrict__ wq,
    const float* __restrict__ wp,
    bf16_t* __restrict__ xb, bf16_t* __restrict__ wqb, bf16_t* __restrict__ wpb)
{
    size_t i = ((size_t)blockIdx.x * 256 + threadIdx.x) * 4;
    const float* src; bf16_t* dst; size_t off;
    if (i < XSZ)             { src = x;  dst = xb;  off = i; }
    else if (i < XSZ + WQSZ) { src = wq; dst = wqb; off = i - XSZ; }
    else                     { src = wp; dst = wpb; off = i - XSZ - WQSZ; }
    float4 v = *reinterpret_cast<const float4*>(src + off);
    bf16x4 o = { (bf16_t)v.x, (bf16_t)v.y, (bf16_t)v.z, (bf16_t)v.w };
    *reinterpret_cast<bf16x4*>(dst + off) = o;
}

// ---------------------------------------------------------------------------
// QKV GEMM, m97-style: 128x128 tile, BK=32, staging via global_load_lds
// width=16 into CONTIGUOUS [128][32] LDS. 2 barriers per K-step.
// Epilogue scatter: t=0: Q[h][m][d] (*SCALE_L2E)  t=1: K[h][m][d]
//                   t=2: Vt[h][d][m] (8B stores)
// ---------------------------------------------------------------------------
__global__ __launch_bounds__(256) void qkv_gemm_kernel(
    const bf16_t* __restrict__ X, const bf16_t* __restrict__ W,
    bf16_t* __restrict__ Qo, bf16_t* __restrict__ Ko, bf16_t* __restrict__ Vt)
{
    __shared__ __align__(16) bf16_t As[128 * 32];
    __shared__ __align__(16) bf16_t Bs[128 * 32];
    const int tid  = threadIdx.x;
    const int wave = tid >> 6, lane = tid & 63;
    const int lr = lane & 15, lq = lane >> 4;
    const int M0 = blockIdx.x * 128;
    const int N0 = blockIdx.y * 128;
    const int wm = (wave >> 1) * 64, wn = (wave & 1) * 64;

    const int g_row = wave * 32 + (lane >> 2);     // + c*16
    const int g_col = (lane & 3) * 8;

    f32x4 acc[4][4] = {};

    for (int k0 = 0; k0 < DIM; k0 += 32) {
        #pragma unroll
        for (int c = 0; c < 2; ++c) {
            gl2lds16(&X[(size_t)(M0 + g_row + c * 16) * DIM + k0 + g_col],
                     &As[(wave * 32 + c * 16) * 32]);
            gl2lds16(&W[(size_t)(N0 + g_row + c * 16) * DIM + k0 + g_col],
                     &Bs[(wave * 32 + c * 16) * 32]);
        }
        __syncthreads();   // drains vmcnt: LDS tiles complete
        bf16x8 af[4], bfr[4];
        #pragma unroll
        for (int i = 0; i < 4; ++i) af[i]  = load8(&As[(wm + i * 16 + lr) * 32 + lq * 8]);
        #pragma unroll
        for (int i = 0; i < 4; ++i) bfr[i] = load8(&Bs[(wn + i * 16 + lr) * 32 + lq * 8]);
        #pragma unroll
        for (int r = 0; r < 4; ++r)
            #pragma unroll
            for (int c = 0; c < 4; ++c)
                acc[r][c] = __builtin_amdgcn_mfma_f32_16x16x32_bf16(af[r], bfr[c], acc[r][c], 0, 0, 0);
        __syncthreads();   // protect LDS before next overwrite
    }

    const int t = N0 / DIM;      // uniform per block (768 % 128 == 0)
    if (t == 2) {
        #pragma unroll
        for (int r = 0; r < 4; ++r)
            #pragma unroll
            for (int c = 0; c < 4; ++c) {
                int m0 = M0 + wm + r * 16 + lq * 4;
                int rem = N0 + wn + c * 16 + lr - 2 * DIM;
                int hh = rem >> 6, d = rem & 63;
                bf16x4 v = { (bf16_t)acc[r][c][0], (bf16_t)acc[r][c][1],
                             (bf16_t)acc[r][c][2], (bf16_t)acc[r][c][3] };
                *reinterpret_cast<bf16x4*>(&Vt[((size_t)hh * HD + d) * NTOK + m0]) = v;
            }
    } else {
        #pragma unroll
        for (int r = 0; r < 4; ++r)
            #pragma unroll
            for (int c = 0; c < 4; ++c)
                #pragma unroll
                for (int reg = 0; reg < 4; ++reg) {
                    int m = M0 + wm + r * 16 + lq * 4 + reg;
                    int rem = N0 + wn + c * 16 + lr - t * DIM;
                    int hh = rem >> 6, d = rem & 63;
                    float v = acc[r][c][reg];
                    if (t == 0) Qo[(hh * NTOK + m) * HD + d] = (bf16_t)(v * SCALE_L2E);
                    else        Ko[(hh * NTOK + m) * HD + d] = (bf16_t)v;
                }
    }
}

// ---------------------------------------------------------------------------
// Flash attention, S^T form, static-shift softmax, split-K=4.
// *** 512-thread blocks (8 waves), 256 q-rows per block. ***
// Rationale (r4/r5 evidence): resident blocks/CU is pinned at ~2 regardless
// of grid size and VGPR count (NSPLIT 2->4 left wall AND occupancy flat at
// ~26-28%); per-pipe accounting shows VALU ~18% / MFMA ~8% of wall ->
// latency-bound at ~2 waves/SIMD. Doubling waves PER BLOCK doubles resident
// waves under a block-count cap; per-wave work/regs/LDS are unchanged.
// Also: staging is now exactly 1 gl2lds call each for K and V per thread
// (512 lanes x 16B = the full 8KB tile), and K/V HBM fetch halves.
//
// XOR-swizzled stride-64 LDS: cell (row, swgroup) holds original column
// group swgroup ^ (row&7). Reads (unchanged): kc0/kc1, vc[g] lane consts.
// Staging via global_load_lds: LDS dest LINEAR (wave base + lane*16); the
// swizzle lives in the per-lane GLOBAL source column: wave w, lane l stages
// row w*8 + l/8 (row&7 = l/8), swgroup l%8 => src col group (l%8)^(l/8).
// Race (one barrier/iter): stage(it+1 -> buf^1) issues after barrier(end
// it-1), when all waves finished reading buf^1; __syncthreads drains each
// wave's vmcnt so buf^1 is complete before compute(it+1).
//
// Softmax row-sum via ones-MFMA: C[i][j] = sum_k 1*P[k][j] -> every C row
// holds the key-group sum of the SAME bf16-rounded p used in PV; la=lsA[0],
// no per-element v_add chain, no final shuffles (moves ~64 VALU cyc/iter to
// the idle matrix pipe).
// QK accumulators init to -SOFTMAX_C (sub folded into MFMA C-in).
// NOTE: plain __launch_bounds__(512); (N,waves) hints force arch/acc split
// and spill (r2: 48 VGPR, 432 MB scratch, 242 us).
// ---------------------------------------------------------------------------
__global__ __launch_bounds__(512) void flash_attn_kernel(
    const bf16_t* __restrict__ Qb, const bf16_t* __restrict__ Kb,
    const bf16_t* __restrict__ Vtb, _Float16* __restrict__ Opart,
    float* __restrict__ Lpart)
{
    __shared__ __align__(16) bf16_t Ks[2][64 * 64];   // [key][d]  swizzled
    __shared__ __align__(16) bf16_t Vs[2][64 * 64];   // [d][key]  swizzled
    const int tid  = threadIdx.x;
    const int wave = tid >> 6, lane = tid & 63;       // wave 0..7
    const int lr = lane & 15, lq = lane >> 4;
    const int h  = blockIdx.y;
    const int q0 = blockIdx.x * 256;
    const int sp = blockIdx.z;
    const int kt0 = sp * KHALF;
    const int NIT = KHALF / 64;     // 16

    // read-side swizzle constants (elements) -- unchanged from r3..r5
    const int kc0 = (lq ^ (lr & 7)) * 8;                             // K frag d 0..31
    const int kc1 = ((4 + lq) ^ (lr & 7)) * 8;                       // K frag d 32..63
    int vc[4];
    #pragma unroll
    for (int g = 0; g < 4; ++g)
        vc[g] = ((2 * g + (lq >> 1)) ^ (lr & 7)) * 8 + (lq & 1) * 4; // V frag keys

    // staging: wave w covers rows w*8 .. w*8+8 of the 64-row tile, 1 call
    const int srow = lane >> 3;                        // 0..7
    const int scol = ((lane & 7) ^ srow) * 8;          // inverse-swizzled col
    const bf16_t* kbase = &Kb[(size_t)h * NTOK * HD];
    const bf16_t* vbase = &Vtb[(size_t)h * HD * NTOK];
    const size_t kof = (size_t)(wave * 8 + srow) * HD + scol;
    const size_t vof = (size_t)(wave * 8 + srow) * NTOK + scol;
    const int ldw = (wave * 8) * 64;       // wave-uniform LDS dest (elements)

    // Q as B-operand of S^T for two q-subtiles (rows +lr and +16+lr)
    const bf16_t* qrowA = &Qb[((size_t)h * NTOK + q0 + wave * 32 + lr) * HD];
    const bf16_t* qrowB = qrowA + 16 * HD;
    bf16x8 qa0 = load8(&qrowA[lq * 8]);
    bf16x8 qa1 = load8(&qrowA[32 + lq * 8]);
    bf16x8 qb0 = load8(&qrowB[lq * 8]);
    bf16x8 qb1 = load8(&qrowB[32 + lq * 8]);

    f32x4 oA[4] = {}, oB[4] = {};
    f32x4 lsA = {}, lsB = {};                     // ones-MFMA row-sum acc
    const f32x4 mc = { -SOFTMAX_C, -SOFTMAX_C, -SOFTMAX_C, -SOFTMAX_C };
    const short ONE = (short)0x3F80;              // bf16 1.0
    const s16x4 ones = { ONE, ONE, ONE, ONE };

    // prologue: stage tile 0 into buf 0
    gl2lds16(kbase + (size_t)kt0 * HD + kof, &Ks[0][ldw]);
    gl2lds16(vbase + kt0 + vof,              &Vs[0][ldw]);
    __syncthreads();

    for (int it = 0; it < NIT; ++it) {
        const int buf = it & 1;

        // stage next tile direct to LDS buf^1; completes by next barrier
        if (it + 1 < NIT) {
            const int kn = kt0 + (it + 1) * 64;
            gl2lds16(kbase + (size_t)kn * HD + kof, &Ks[buf ^ 1][ldw]);
            gl2lds16(vbase + kn + vof,              &Vs[buf ^ 1][ldw]);
        }

        // fused per key-group: QK -> exp2 -> pack -> PV (+ones row-sum)
        #pragma unroll
        for (int g = 0; g < 4; ++g) {
            bf16x8 k0 = load8(&Ks[buf][(g * 16 + lr) * 64 + kc0]);
            bf16x8 k1 = load8(&Ks[buf][(g * 16 + lr) * 64 + kc1]);
            f32x4 za = mc, zb = mc;
            __builtin_amdgcn_s_setprio(1);
            za = __builtin_amdgcn_mfma_f32_16x16x32_bf16(k0, qa0, za, 0, 0, 0);
            za = __builtin_amdgcn_mfma_f32_16x16x32_bf16(k1, qa1, za, 0, 0, 0);
            zb = __builtin_amdgcn_mfma_f32_16x16x32_bf16(k0, qb0, zb, 0, 0, 0);
            zb = __builtin_amdgcn_mfma_f32_16x16x32_bf16(k1, qb1, zb, 0, 0, 0);
            __builtin_amdgcn_s_setprio(0);
            #pragma unroll
            for (int r = 0; r < 4; ++r) {
                za[r] = __builtin_amdgcn_exp2f(za[r]);
                zb[r] = __builtin_amdgcn_exp2f(zb[r]);
            }
            bf16x4 pa = { (bf16_t)za[0], (bf16_t)za[1],
                          (bf16_t)za[2], (bf16_t)za[3] };
            bf16x4 pb = { (bf16_t)zb[0], (bf16_t)zb[1],
                          (bf16_t)zb[2], (bf16_t)zb[3] };
            s16x4 psa = __builtin_bit_cast(s16x4, pa);
            s16x4 psb = __builtin_bit_cast(s16x4, pb);
            __builtin_amdgcn_s_setprio(1);
            lsA = __builtin_amdgcn_mfma_f32_16x16x16bf16_1k(ones, psa, lsA, 0, 0, 0);
            lsB = __builtin_amdgcn_mfma_f32_16x16x16bf16_1k(ones, psb, lsB, 0, 0, 0);
            #pragma unroll
            for (int dt = 0; dt < 4; ++dt) {
                s16x4 va = *reinterpret_cast<const s16x4*>(
                    &Vs[buf][(dt * 16 + lr) * 64 + vc[g]]);
                oA[dt] = __builtin_amdgcn_mfma_f32_16x16x16bf16_1k(va, psa, oA[dt], 0, 0, 0);
                oB[dt] = __builtin_amdgcn_mfma_f32_16x16x16bf16_1k(va, psb, oB[dt], 0, 0, 0);
            }
            __builtin_amdgcn_s_setprio(0);
        }

        __syncthreads();   // drains own gl2lds (next buf ready) + protects buf
    }

    // every C row of the ones-MFMA holds the row-sum for q-col lr
    const float la = lsA[0], lb = lsB[0];
    const int ma = q0 + wave * 32 + lr;
    const int mb = ma + 16;
    if (lq == 0) {
        Lpart[((size_t)sp * NH + h) * NTOK + ma] = la;
        Lpart[((size_t)sp * NH + h) * NTOK + mb] = lb;
    }
    _Float16* oa = &Opart[((size_t)sp * NTOK + ma) * DIM + h * HD];
    _Float16* ob = &Opart[((size_t)sp * NTOK + mb) * DIM + h * HD];
    #pragma unroll
    for (int dt = 0; dt < 4; ++dt) {
        f16x4 va = { (_Float16)oA[dt][0], (_Float16)oA[dt][1],
                     (_Float16)oA[dt][2], (_Float16)oA[dt][3] };
        f16x4 vb = { (_Float16)oB[dt][0], (_Float16)oB[dt][1],
                     (_Float16)oB[dt][2], (_Float16)oB[dt][3] };
        *reinterpret_cast<f16x4*>(&oa[dt * 16 + lq * 4]) = va;
        *reinterpret_cast<f16x4*>(&ob[dt * 16 + lq * 4]) = vb;
    }
}

// ---------------------------------------------------------------------------
// Split-K combine: one pass over the NSPLIT fp16 partials, normalize by the
// summed softmax denominators, emit bf16 A for the proj GEMM.
// ---------------------------------------------------------------------------
__global__ __launch_bounds__(256) void combine_kernel(
    const _Float16* __restrict__ Opart, const float* __restrict__ Lpart,
    bf16_t* __restrict__ Ab)
{
    int idx = blockIdx.x * 256 + threadIdx.x;       // over NTOK*DIM/4
    int m = idx / (DIM / 4);
    int c = (idx - m * (DIM / 4)) * 4;
    int hh = c >> 6;
    float l = 0.f;
    #pragma unroll
    for (int s = 0; s < NSPLIT; ++s)
        l += Lpart[((size_t)s * NH + hh) * NTOK + m];
    float rv = 1.f / l;
    float a0 = 0.f, a1 = 0.f, a2 = 0.f, a3 = 0.f;
    #pragma unroll
    for (int s = 0; s < NSPLIT; ++s) {
        f16x4 v = *reinterpret_cast<const f16x4*>(
            &Opart[((size_t)s * NTOK + m) * DIM + c]);
        a0 += (float)v[0]; a1 += (float)v[1];
        a2 += (float)v[2]; a3 += (float)v[3];
    }
    bf16x4 o = { (bf16_t)(a0 * rv), (bf16_t)(a1 * rv),
                 (bf16_t)(a2 * rv), (bf16_t)(a3 * rv) };
    *reinterpret_cast<bf16x4*>(&Ab[(size_t)m * DIM + c]) = o;
}

// ---------------------------------------------------------------------------
// Proj GEMM: plain bf16 GEMM out = A @ Wp^T + bias, 64x64 tile, BK=32,
// gl2lds16 staging into contiguous [64][32] LDS (bank-uniform for b128
// frag reads).
// ---------------------------------------------------------------------------
__global__ __launch_bounds__(256) void proj_gemm_kernel(
    const bf16_t* __restrict__ A, const bf16_t* __restrict__ W,
    const float* __restrict__ bias, float* __restrict__ out)
{
    __shared__ __align__(16) bf16_t As[64 * 32];
    __shared__ __align__(16) bf16_t Bs[64 * 32];
    const int tid  = threadIdx.x;
    const int wave = tid >> 6, lane = tid & 63;
    const int lr = lane & 15, lq = lane >> 4;
    const int M0 = blockIdx.x * 64;
    const int N0 = blockIdx.y * 64;
    const int wr = (wave >> 1) * 32, wc = (wave & 1) * 32;
    const int g_row = tid >> 2;           // 0..63
    const int g_col = (tid & 3) * 8;

    f32x4 acc[2][2] = {};

    for (int k0 = 0; k0 < DIM; k0 += 32) {
        gl2lds16(&A[(size_t)(M0 + g_row) * DIM + k0 + g_col], &As[wave * 512]);
        gl2lds16(&W[(size_t)(N0 + g_row) * DIM + k0 + g_col], &Bs[wave * 512]);
        __syncthreads();
        bf16x8 a0 = load8(&As[(wr + lr) * 32 + lq * 8]);
        bf16x8 a1 = load8(&As[(wr + 16 + lr) * 32 + lq * 8]);
        bf16x8 b0 = load8(&Bs[(wc + lr) * 32 + lq * 8]);
        bf16x8 b1 = load8(&Bs[(wc + 16 + lr) * 32 + lq * 8]);
        acc[0][0] = __builtin_amdgcn_mfma_f32_16x16x32_bf16(a0, b0, acc[0][0], 0, 0, 0);
        acc[0][1] = __builtin_amdgcn_mfma_f32_16x16x32_bf16(a0, b1, acc[0][1], 0, 0, 0);
        acc[1][0] = __builtin_amdgcn_mfma_f32_16x16x32_bf16(a1, b0, acc[1][0], 0, 0, 0);
        acc[1][1] = __builtin_amdgcn_mfma_f32_16x16x32_bf16(a1, b1, acc[1][1], 0, 0, 0);
        __syncthreads();
    }

    #pragma unroll
    for (int r = 0; r < 2; ++r)
        #pragma unroll
        for (int c = 0; c < 2; ++c)
            #pragma unroll
            for (int reg = 0; reg < 4; ++reg) {
                int m = M0 + wr + r * 16 + lq * 4 + reg;
                int n = N0 + wc + c * 16 + lr;
                out[(size_t)m * DIM + n] = acc[r][c][reg] + bias[n];
            }
}

// ---------------------------------------------------------------------------
// Workspace layout (55,050,240 B total -- strictly within the proven
// 55,443,456 B envelope from rounds 2/3):
//   [0, 3sz)          Q | K | Vt   (flash inputs; Q reused as Ab after flash)
//   [3sz, +XSZ*2)     xb           (dead after qkv; Lpart lives at its base)
//   [.., +WQSZ*2)     wqb          (dead after qkv)
//   [.., +WPSZ*2)     wpb          (live until proj)
//   [.., +25.2MB)     Opart fp16   (NSPLIT=4)
// ---------------------------------------------------------------------------
extern "C" void kernel_launch(void* const* d_in, const int* in_sizes, int n_in,
                              void* d_out, int out_size, void* d_ws, size_t ws_size,
                              hipStream_t stream)
{
    const float* x      = (const float*)d_in[0];
    const float* w_qkv  = (const float*)d_in[1];
    const float* w_proj = (const float*)d_in[2];
    const float* b_proj = (const float*)d_in[3];
    float* out = (float*)d_out;

    char* ws = (char*)d_ws;
    const size_t sz = (size_t)NH * NTOK * HD * sizeof(bf16_t);  // 6,291,456 B
    bf16_t*   Q     = (bf16_t*)(ws);
    bf16_t*   K     = (bf16_t*)(ws + sz);
    bf16_t*   Vt    = (bf16_t*)(ws + 2 * sz);
    bf16_t*   xb    = (bf16_t*)(ws + 3 * sz);
    bf16_t*   wqb   = (bf16_t*)(ws + 3 * sz + (size_t)XSZ * 2);
    bf16_t*   wpb   = (bf16_t*)(ws + 3 * sz + (size_t)(XSZ + WQSZ) * 2);
    _Float16* Opart = (_Float16*)(ws + 3 * sz + (size_t)(XSZ + WQSZ + WPSZ) * 2);
    float*    Lpart = (float*)xb;   // xb dead after qkv_gemm; 786,432 B fits
    bf16_t*   Ab    = Q;            // Q dead after flash_attn

    cvt_kernel<<<dim3((XSZ + WQSZ + WPSZ) / 1024), 256, 0, stream>>>(
        x, w_qkv, w_proj, xb, wqb, wpb);
    qkv_gemm_kernel<<<dim3(NTOK / 128, (3 * DIM) / 128), 256, 0, stream>>>(
        xb, wqb, Q, K, Vt);
    flash_attn_kernel<<<dim3(NTOK / 256, NH, NSPLIT), 512, 0, stream>>>(
        Q, K, Vt, Opart, Lpart);
    combine_kernel<<<dim3((NTOK * DIM / 4) / 256), 256, 0, stream>>>(
        Opart, Lpart, Ab);
    proj_gemm_kernel<<<dim3(NTOK / 64, DIM / 64), 256, 0, stream>>>(
        Ab, wpb, b_proj, out);
}

// Round 8
// 186.522 us; speedup vs baseline: 1.0064x; 1.0053x over previous
//
#include <hip/hip_runtime.h>
#include <hip/hip_bf16.h>

typedef __bf16 bf16_t;
typedef __attribute__((ext_vector_type(8))) __bf16 bf16x8;
typedef __attribute__((ext_vector_type(4))) __bf16 bf16x4;
typedef __attribute__((ext_vector_type(4))) short s16x4;
typedef __attribute__((ext_vector_type(4))) float f32x4;
typedef __attribute__((ext_vector_type(4))) _Float16 f16x4;

#define NTOK 4096
#define DIM  768
#define NH   12
#define HD   64
#define NSPLIT 4
#define KHALF (NTOK / NSPLIT)   // 1024 -> NIT=16
#define XSZ  (NTOK * DIM)       // 3,145,728
#define WQSZ (3 * DIM * DIM)    // 1,769,472
#define WPSZ (DIM * DIM)        //   589,824
// 0.125 * log2(e): folded into Q so S^T is directly in log2 domain
#define SCALE_L2E 0.18033688011112042f
// static softmax shift (shift-invariant, no overflow for |st|<~15)
#define SOFTMAX_C 12.0f

__device__ __forceinline__ bf16x8 load8(const bf16_t* p) {
    return *reinterpret_cast<const bf16x8*>(p);
}
__device__ __forceinline__ void store8(bf16_t* p, bf16x8 v) {
    *reinterpret_cast<bf16x8*>(p) = v;
}
// async global->LDS, 16B per lane; LDS dest = wave-uniform base + lane*16
__device__ __forceinline__ void gl2lds16(const bf16_t* g, bf16_t* l) {
    __builtin_amdgcn_global_load_lds(
        (const __attribute__((address_space(1))) void*)g,
        (__attribute__((address_space(3))) void*)l, 16, 0, 0);
}

// ---------------------------------------------------------------------------
// Convert fp32 inputs to bf16 once (memory-bound, ~33 MB total).
// ---------------------------------------------------------------------------
__global__ __launch_bounds__(256) void cvt_kernel(
    const float* __restrict__ x, const float* __restrict__ wq,
    const float* __restrict__ wp,
    bf16_t* __restrict__ xb, bf16_t* __restrict__ wqb, bf16_t* __restrict__ wpb)
{
    size_t i = ((size_t)blockIdx.x * 256 + threadIdx.x) * 4;
    const float* src; bf16_t* dst; size_t off;
    if (i < XSZ)             { src = x;  dst = xb;  off = i; }
    else if (i < XSZ + WQSZ) { src = wq; dst = wqb; off = i - XSZ; }
    else                     { src = wp; dst = wpb; off = i - XSZ - WQSZ; }
    float4 v = *reinterpret_cast<const float4*>(src + off);
    bf16x4 o = { (bf16_t)v.x, (bf16_t)v.y, (bf16_t)v.z, (bf16_t)v.w };
    *reinterpret_cast<bf16x4*>(dst + off) = o;
}

// ---------------------------------------------------------------------------
// QKV GEMM, m97-style: 128x128 tile, BK=32, staging via global_load_lds
// width=16 into CONTIGUOUS [128][32] LDS. 2 barriers per K-step.
// Epilogue scatter: t=0: Q[h][m][d] (*SCALE_L2E)  t=1: K[h][m][d]
//                   t=2: Vt[h][d][m] (8B stores)
// ---------------------------------------------------------------------------
__global__ __launch_bounds__(256) void qkv_gemm_kernel(
    const bf16_t* __restrict__ X, const bf16_t* __restrict__ W,
    bf16_t* __restrict__ Qo, bf16_t* __restrict__ Ko, bf16_t* __restrict__ Vt)
{
    __shared__ __align__(16) bf16_t As[128 * 32];
    __shared__ __align__(16) bf16_t Bs[128 * 32];
    const int tid  = threadIdx.x;
    const int wave = tid >> 6, lane = tid & 63;
    const int lr = lane & 15, lq = lane >> 4;
    const int M0 = blockIdx.x * 128;
    const int N0 = blockIdx.y * 128;
    const int wm = (wave >> 1) * 64, wn = (wave & 1) * 64;

    const int g_row = wave * 32 + (lane >> 2);     // + c*16
    const int g_col = (lane & 3) * 8;

    f32x4 acc[4][4] = {};

    for (int k0 = 0; k0 < DIM; k0 += 32) {
        #pragma unroll
        for (int c = 0; c < 2; ++c) {
            gl2lds16(&X[(size_t)(M0 + g_row + c * 16) * DIM + k0 + g_col],
                     &As[(wave * 32 + c * 16) * 32]);
            gl2lds16(&W[(size_t)(N0 + g_row + c * 16) * DIM + k0 + g_col],
                     &Bs[(wave * 32 + c * 16) * 32]);
        }
        __syncthreads();   // drains vmcnt: LDS tiles complete
        bf16x8 af[4], bfr[4];
        #pragma unroll
        for (int i = 0; i < 4; ++i) af[i]  = load8(&As[(wm + i * 16 + lr) * 32 + lq * 8]);
        #pragma unroll
        for (int i = 0; i < 4; ++i) bfr[i] = load8(&Bs[(wn + i * 16 + lr) * 32 + lq * 8]);
        #pragma unroll
        for (int r = 0; r < 4; ++r)
            #pragma unroll
            for (int c = 0; c < 4; ++c)
                acc[r][c] = __builtin_amdgcn_mfma_f32_16x16x32_bf16(af[r], bfr[c], acc[r][c], 0, 0, 0);
        __syncthreads();   // protect LDS before next overwrite
    }

    const int t = N0 / DIM;      // uniform per block (768 % 128 == 0)
    if (t == 2) {
        #pragma unroll
        for (int r = 0; r < 4; ++r)
            #pragma unroll
            for (int c = 0; c < 4; ++c) {
                int m0 = M0 + wm + r * 16 + lq * 4;
                int rem = N0 + wn + c * 16 + lr - 2 * DIM;
                int hh = rem >> 6, d = rem & 63;
                bf16x4 v = { (bf16_t)acc[r][c][0], (bf16_t)acc[r][c][1],
                             (bf16_t)acc[r][c][2], (bf16_t)acc[r][c][3] };
                *reinterpret_cast<bf16x4*>(&Vt[((size_t)hh * HD + d) * NTOK + m0]) = v;
            }
    } else {
        #pragma unroll
        for (int r = 0; r < 4; ++r)
            #pragma unroll
            for (int c = 0; c < 4; ++c)
                #pragma unroll
                for (int reg = 0; reg < 4; ++reg) {
                    int m = M0 + wm + r * 16 + lq * 4 + reg;
                    int rem = N0 + wn + c * 16 + lr - t * DIM;
                    int hh = rem >> 6, d = rem & 63;
                    float v = acc[r][c][reg];
                    if (t == 0) Qo[(hh * NTOK + m) * HD + d] = (bf16_t)(v * SCALE_L2E);
                    else        Ko[(hh * NTOK + m) * HD + d] = (bf16_t)v;
                }
    }
}

// ---------------------------------------------------------------------------
// Flash attention, S^T form, static-shift softmax, split-K=4.
// 512-thread blocks (8 waves), 256 q-rows per block (r6: 80us, 48 VGPR).
//
// Counted-vmcnt pipeline (T4), r8 defensive restructure of r7:
//  - prologue stages tiles 0 AND 1, then a normal __syncthreads() (full
//    drain ONCE, ~1500cyc) -- both tiles resident before the loop, and the
//    raw-barrier sequence never precedes an ordinary sync.
//  - loop: compute(buf) -> lgkmcnt(0)+barrier (reads retired) ->
//    stage(it+2 -> buf) -> vmcnt(2) (tile it+1's loads done; only the
//    2 just-issued stay in flight) -> barrier (tile it+1 block-visible).
//    Tail (it+2>=NIT): vmcnt(0) drain instead.
//  Each tile's HBM loads get >= one full compute phase to land instead of
//  being drained at every barrier (r6: vmcnt(0) drain each iter, ~600-900
//  cyc serialized x16; wall ~4000 cyc/block-iter vs ~400 cyc pipe work).
//  vmcnt counting is per-wave and robust: every wave waits on its OWN two
//  newest ops (always the just-issued stage) before the barrier, so after
//  the barrier the whole tile is complete block-wide.
//
// XOR-swizzled stride-64 LDS: cell (row, swgroup) holds original column
// group swgroup ^ (row&7). Reads: kc0/kc1, vc[g] lane consts. Staging via
// global_load_lds: LDS dest LINEAR; swizzle lives in the per-lane GLOBAL
// source column (wave w, lane l: row w*8+l/8, src col group (l%8)^(l/8)).
// Softmax row-sum via ones-MFMA (la = lsA[0]); QK acc init -SOFTMAX_C.
// NOTE: plain __launch_bounds__(512); (N,waves) hints force arch/acc split
// and spill (r2: 48 VGPR, 432 MB scratch, 242 us).
// ---------------------------------------------------------------------------
__global__ __launch_bounds__(512) void flash_attn_kernel(
    const bf16_t* __restrict__ Qb, const bf16_t* __restrict__ Kb,
    const bf16_t* __restrict__ Vtb, _Float16* __restrict__ Opart,
    float* __restrict__ Lpart)
{
    __shared__ __align__(16) bf16_t Ks[2][64 * 64];   // [key][d]  swizzled
    __shared__ __align__(16) bf16_t Vs[2][64 * 64];   // [d][key]  swizzled
    const int tid  = threadIdx.x;
    const int wave = tid >> 6, lane = tid & 63;       // wave 0..7
    const int lr = lane & 15, lq = lane >> 4;
    const int h  = blockIdx.y;
    const int q0 = blockIdx.x * 256;
    const int sp = blockIdx.z;
    const int kt0 = sp * KHALF;
    const int NIT = KHALF / 64;     // 16

    // read-side swizzle constants (elements) -- unchanged from r3..r6
    const int kc0 = (lq ^ (lr & 7)) * 8;                             // K frag d 0..31
    const int kc1 = ((4 + lq) ^ (lr & 7)) * 8;                       // K frag d 32..63
    int vc[4];
    #pragma unroll
    for (int g = 0; g < 4; ++g)
        vc[g] = ((2 * g + (lq >> 1)) ^ (lr & 7)) * 8 + (lq & 1) * 4; // V frag keys

    // staging: wave w covers rows w*8 .. w*8+8 of the 64-row tile, 1 call
    const int srow = lane >> 3;                        // 0..7
    const int scol = ((lane & 7) ^ srow) * 8;          // inverse-swizzled col
    const bf16_t* kbase = &Kb[(size_t)h * NTOK * HD];
    const bf16_t* vbase = &Vtb[(size_t)h * HD * NTOK];
    const size_t kof = (size_t)(wave * 8 + srow) * HD + scol;
    const size_t vof = (size_t)(wave * 8 + srow) * NTOK + scol;
    const int ldw = (wave * 8) * 64;       // wave-uniform LDS dest (elements)

    // Q as B-operand of S^T for two q-subtiles (rows +lr and +16+lr)
    const bf16_t* qrowA = &Qb[((size_t)h * NTOK + q0 + wave * 32 + lr) * HD];
    const bf16_t* qrowB = qrowA + 16 * HD;
    bf16x8 qa0 = load8(&qrowA[lq * 8]);
    bf16x8 qa1 = load8(&qrowA[32 + lq * 8]);
    bf16x8 qb0 = load8(&qrowB[lq * 8]);
    bf16x8 qb1 = load8(&qrowB[32 + lq * 8]);

    f32x4 oA[4] = {}, oB[4] = {};
    f32x4 lsA = {}, lsB = {};                     // ones-MFMA row-sum acc
    const f32x4 mc = { -SOFTMAX_C, -SOFTMAX_C, -SOFTMAX_C, -SOFTMAX_C };
    const short ONE = (short)0x3F80;              // bf16 1.0
    const s16x4 ones = { ONE, ONE, ONE, ONE };

    // prologue: stage tiles 0 and 1, then ONE full drain
    gl2lds16(kbase + (size_t)kt0 * HD + kof, &Ks[0][ldw]);
    gl2lds16(vbase + kt0 + vof,              &Vs[0][ldw]);
    gl2lds16(kbase + (size_t)(kt0 + 64) * HD + kof, &Ks[1][ldw]);
    gl2lds16(vbase + (kt0 + 64) + vof,              &Vs[1][ldw]);
    __syncthreads();                   // tiles 0 AND 1 resident block-wide

    for (int it = 0; it < NIT; ++it) {
        const int buf = it & 1;

        // fused per key-group: QK -> exp2 -> pack -> PV (+ones row-sum)
        #pragma unroll
        for (int g = 0; g < 4; ++g) {
            bf16x8 k0 = load8(&Ks[buf][(g * 16 + lr) * 64 + kc0]);
            bf16x8 k1 = load8(&Ks[buf][(g * 16 + lr) * 64 + kc1]);
            f32x4 za = mc, zb = mc;
            __builtin_amdgcn_s_setprio(1);
            za = __builtin_amdgcn_mfma_f32_16x16x32_bf16(k0, qa0, za, 0, 0, 0);
            za = __builtin_amdgcn_mfma_f32_16x16x32_bf16(k1, qa1, za, 0, 0, 0);
            zb = __builtin_amdgcn_mfma_f32_16x16x32_bf16(k0, qb0, zb, 0, 0, 0);
            zb = __builtin_amdgcn_mfma_f32_16x16x32_bf16(k1, qb1, zb, 0, 0, 0);
            __builtin_amdgcn_s_setprio(0);
            #pragma unroll
            for (int r = 0; r < 4; ++r) {
                za[r] = __builtin_amdgcn_exp2f(za[r]);
                zb[r] = __builtin_amdgcn_exp2f(zb[r]);
            }
            bf16x4 pa = { (bf16_t)za[0], (bf16_t)za[1],
                          (bf16_t)za[2], (bf16_t)za[3] };
            bf16x4 pb = { (bf16_t)zb[0], (bf16_t)zb[1],
                          (bf16_t)zb[2], (bf16_t)zb[3] };
            s16x4 psa = __builtin_bit_cast(s16x4, pa);
            s16x4 psb = __builtin_bit_cast(s16x4, pb);
            __builtin_amdgcn_s_setprio(1);
            lsA = __builtin_amdgcn_mfma_f32_16x16x16bf16_1k(ones, psa, lsA, 0, 0, 0);
            lsB = __builtin_amdgcn_mfma_f32_16x16x16bf16_1k(ones, psb, lsB, 0, 0, 0);
            #pragma unroll
            for (int dt = 0; dt < 4; ++dt) {
                s16x4 va = *reinterpret_cast<const s16x4*>(
                    &Vs[buf][(dt * 16 + lr) * 64 + vc[g]]);
                oA[dt] = __builtin_amdgcn_mfma_f32_16x16x16bf16_1k(va, psa, oA[dt], 0, 0, 0);
                oB[dt] = __builtin_amdgcn_mfma_f32_16x16x16bf16_1k(va, psb, oB[dt], 0, 0, 0);
            }
            __builtin_amdgcn_s_setprio(0);
        }

        if (it == NIT - 1) break;      // last tile: no restage, no wait

        // my LDS reads retired -> safe for others to overwrite after barrier
        asm volatile("s_waitcnt lgkmcnt(0)" ::: "memory");
        __builtin_amdgcn_sched_barrier(0);
        __builtin_amdgcn_s_barrier();      // all waves done reading buf

        if (it + 2 < NIT) {
            const int kn = kt0 + (it + 2) * 64;
            gl2lds16(kbase + (size_t)kn * HD + kof, &Ks[buf][ldw]);
            gl2lds16(vbase + kn + vof,              &Vs[buf][ldw]);
            // tile it+1 complete (only the 2 just-issued stay in flight)
            asm volatile("s_waitcnt vmcnt(2)" ::: "memory");
        } else {
            asm volatile("s_waitcnt vmcnt(0)" ::: "memory");  // tail drain
        }
        __builtin_amdgcn_sched_barrier(0);
        __builtin_amdgcn_s_barrier();      // tile it+1 visible block-wide
    }

    // every C row of the ones-MFMA holds the row-sum for q-col lr
    const float la = lsA[0], lb = lsB[0];
    const int ma = q0 + wave * 32 + lr;
    const int mb = ma + 16;
    if (lq == 0) {
        Lpart[((size_t)sp * NH + h) * NTOK + ma] = la;
        Lpart[((size_t)sp * NH + h) * NTOK + mb] = lb;
    }
    _Float16* oa = &Opart[((size_t)sp * NTOK + ma) * DIM + h * HD];
    _Float16* ob = &Opart[((size_t)sp * NTOK + mb) * DIM + h * HD];
    #pragma unroll
    for (int dt = 0; dt < 4; ++dt) {
        f16x4 va = { (_Float16)oA[dt][0], (_Float16)oA[dt][1],
                     (_Float16)oA[dt][2], (_Float16)oA[dt][3] };
        f16x4 vb = { (_Float16)oB[dt][0], (_Float16)oB[dt][1],
                     (_Float16)oB[dt][2], (_Float16)oB[dt][3] };
        *reinterpret_cast<f16x4*>(&oa[dt * 16 + lq * 4]) = va;
        *reinterpret_cast<f16x4*>(&ob[dt * 16 + lq * 4]) = vb;
    }
}

// ---------------------------------------------------------------------------
// Split-K combine: one pass over the NSPLIT fp16 partials, normalize by the
// summed softmax denominators, emit bf16 A for the proj GEMM.
// ---------------------------------------------------------------------------
__global__ __launch_bounds__(256) void combine_kernel(
    const _Float16* __restrict__ Opart, const float* __restrict__ Lpart,
    bf16_t* __restrict__ Ab)
{
    int idx = blockIdx.x * 256 + threadIdx.x;       // over NTOK*DIM/4
    int m = idx / (DIM / 4);
    int c = (idx - m * (DIM / 4)) * 4;
    int hh = c >> 6;
    float l = 0.f;
    #pragma unroll
    for (int s = 0; s < NSPLIT; ++s)
        l += Lpart[((size_t)s * NH + hh) * NTOK + m];
    float rv = 1.f / l;
    float a0 = 0.f, a1 = 0.f, a2 = 0.f, a3 = 0.f;
    #pragma unroll
    for (int s = 0; s < NSPLIT; ++s) {
        f16x4 v = *reinterpret_cast<const f16x4*>(
            &Opart[((size_t)s * NTOK + m) * DIM + c]);
        a0 += (float)v[0]; a1 += (float)v[1];
        a2 += (float)v[2]; a3 += (float)v[3];
    }
    bf16x4 o = { (bf16_t)(a0 * rv), (bf16_t)(a1 * rv),
                 (bf16_t)(a2 * rv), (bf16_t)(a3 * rv) };
    *reinterpret_cast<bf16x4*>(&Ab[(size_t)m * DIM + c]) = o;
}

// ---------------------------------------------------------------------------
// Proj GEMM: plain bf16 GEMM out = A @ Wp^T + bias, 64x64 tile, BK=32,
// gl2lds16 staging into contiguous [64][32] LDS (bank-uniform for b128
// frag reads).
// ---------------------------------------------------------------------------
__global__ __launch_bounds__(256) void proj_gemm_kernel(
    const bf16_t* __restrict__ A, const bf16_t* __restrict__ W,
    const float* __restrict__ bias, float* __restrict__ out)
{
    __shared__ __align__(16) bf16_t As[64 * 32];
    __shared__ __align__(16) bf16_t Bs[64 * 32];
    const int tid  = threadIdx.x;
    const int wave = tid >> 6, lane = tid & 63;
    const int lr = lane & 15, lq = lane >> 4;
    const int M0 = blockIdx.x * 64;
    const int N0 = blockIdx.y * 64;
    const int wr = (wave >> 1) * 32, wc = (wave & 1) * 32;
    const int g_row = tid >> 2;           // 0..63
    const int g_col = (tid & 3) * 8;

    f32x4 acc[2][2] = {};

    for (int k0 = 0; k0 < DIM; k0 += 32) {
        gl2lds16(&A[(size_t)(M0 + g_row) * DIM + k0 + g_col], &As[wave * 512]);
        gl2lds16(&W[(size_t)(N0 + g_row) * DIM + k0 + g_col], &Bs[wave * 512]);
        __syncthreads();
        bf16x8 a0 = load8(&As[(wr + lr) * 32 + lq * 8]);
        bf16x8 a1 = load8(&As[(wr + 16 + lr) * 32 + lq * 8]);
        bf16x8 b0 = load8(&Bs[(wc + lr) * 32 + lq * 8]);
        bf16x8 b1 = load8(&Bs[(wc + 16 + lr) * 32 + lq * 8]);
        acc[0][0] = __builtin_amdgcn_mfma_f32_16x16x32_bf16(a0, b0, acc[0][0], 0, 0, 0);
        acc[0][1] = __builtin_amdgcn_mfma_f32_16x16x32_bf16(a0, b1, acc[0][1], 0, 0, 0);
        acc[1][0] = __builtin_amdgcn_mfma_f32_16x16x32_bf16(a1, b0, acc[1][0], 0, 0, 0);
        acc[1][1] = __builtin_amdgcn_mfma_f32_16x16x32_bf16(a1, b1, acc[1][1], 0, 0, 0);
        __syncthreads();
    }

    #pragma unroll
    for (int r = 0; r < 2; ++r)
        #pragma unroll
        for (int c = 0; c < 2; ++c)
            #pragma unroll
            for (int reg = 0; reg < 4; ++reg) {
                int m = M0 + wr + r * 16 + lq * 4 + reg;
                int n = N0 + wc + c * 16 + lr;
                out[(size_t)m * DIM + n] = acc[r][c][reg] + bias[n];
            }
}

// ---------------------------------------------------------------------------
// Workspace layout (55,050,240 B total -- strictly within the proven
// 55,443,456 B envelope from rounds 2-6):
//   [0, 3sz)          Q | K | Vt   (flash inputs; Q reused as Ab after flash)
//   [3sz, +XSZ*2)     xb           (dead after qkv; Lpart lives at its base)
//   [.., +WQSZ*2)     wqb          (dead after qkv)
//   [.., +WPSZ*2)     wpb          (live until proj)
//   [.., +25.2MB)     Opart fp16   (NSPLIT=4)
// ---------------------------------------------------------------------------
extern "C" void kernel_launch(void* const* d_in, const int* in_sizes, int n_in,
                              void* d_out, int out_size, void* d_ws, size_t ws_size,
                              hipStream_t stream)
{
    const float* x      = (const float*)d_in[0];
    const float* w_qkv  = (const float*)d_in[1];
    const float* w_proj = (const float*)d_in[2];
    const float* b_proj = (const float*)d_in[3];
    float* out = (float*)d_out;

    char* ws = (char*)d_ws;
    const size_t sz = (size_t)NH * NTOK * HD * sizeof(bf16_t);  // 6,291,456 B
    bf16_t*   Q     = (bf16_t*)(ws);
    bf16_t*   K     = (bf16_t*)(ws + sz);
    bf16_t*   Vt    = (bf16_t*)(ws + 2 * sz);
    bf16_t*   xb    = (bf16_t*)(ws + 3 * sz);
    bf16_t*   wqb   = (bf16_t*)(ws + 3 * sz + (size_t)XSZ * 2);
    bf16_t*   wpb   = (bf16_t*)(ws + 3 * sz + (size_t)(XSZ + WQSZ) * 2);
    _Float16* Opart = (_Float16*)(ws + 3 * sz + (size_t)(XSZ + WQSZ + WPSZ) * 2);
    float*    Lpart = (float*)xb;   // xb dead after qkv_gemm; 786,432 B fits
    bf16_t*   Ab    = Q;            // Q dead after flash_attn

    cvt_kernel<<<dim3((XSZ + WQSZ + WPSZ) / 1024), 256, 0, stream>>>(
        x, w_qkv, w_proj, xb, wqb, wpb);
    qkv_gemm_kernel<<<dim3(NTOK / 128, (3 * DIM) / 128), 256, 0, stream>>>(
        xb, wqb, Q, K, Vt);
    flash_attn_kernel<<<dim3(NTOK / 256, NH, NSPLIT), 512, 0, stream>>>(
        Q, K, Vt, Opart, Lpart);
    combine_kernel<<<dim3((NTOK * DIM / 4) / 256), 256, 0, stream>>>(
        Opart, Lpart, Ab);
    proj_gemm_kernel<<<dim3(NTOK / 64, DIM / 64), 256, 0, stream>>>(
        Ab, wpb, b_proj, out);
}